// Round 9
// baseline (3948.962 us; speedup 1.0000x reference)
//
#include <hip/hip_runtime.h>
#include <hip/hip_bf16.h>

// B=8192, T=32, D_IN=2, EMB=128, H=256, 4H=1024
// r9: 128 blocks x 1024 thr (16 waves). Block = 128 batch rows x 512 cols
// (e-half ch of each gate). Pair (b, b^64) same XCD exchanges h-halves via L2
// slabs + pairwise flags each layer. Weight demand/step halves vs r8.
// Per-wave 2-slot LDS ring (depth-1) via global_load_lds, counted vmcnt(1).
// LDS = h0(64K) + h1(64K) + ring(32K) = 163840 B exactly. We/bias/traj from global.

typedef __attribute__((ext_vector_type(8))) __bf16 bf16x8;
typedef __attribute__((ext_vector_type(4))) __bf16 bf16x4;
typedef __attribute__((ext_vector_type(4))) float f32x4;
typedef __attribute__((ext_vector_type(2))) float f32x2;

#define MFMA16(a, b, c) __builtin_amdgcn_mfma_f32_16x16x32_bf16(a, b, c, 0, 0, 0)

// s_waitcnt imm (gfx9): vmcnt[3:0]|[15:14], expcnt[6:4], lgkm[11:8]
#define WAIT_VM1() __builtin_amdgcn_s_waitcnt(0xF71)     // vmcnt(1), others no-wait
#define WAIT_LGKM0() __builtin_amdgcn_s_waitcnt(0xC07F)  // lgkmcnt(0), others no-wait
#define RAW_BARRIER()                \
  do {                               \
    WAIT_LGKM0();                    \
    __builtin_amdgcn_sched_barrier(0); \
    __builtin_amdgcn_s_barrier();    \
  } while (0)

__device__ __forceinline__ float fexp2(float x) {
#if __has_builtin(__builtin_amdgcn_exp2f)
  return __builtin_amdgcn_exp2f(x);
#else
  return exp2f(x);
#endif
}
__device__ __forceinline__ float frcp(float x) {
#if __has_builtin(__builtin_amdgcn_rcpf)
  return __builtin_amdgcn_rcpf(x);
#else
  return 1.0f / x;
#endif
}
__device__ __forceinline__ float fsig(float x) {
  return frcp(1.0f + fexp2(-1.44269504f * x));
}
__device__ __forceinline__ float ftanh(float x) {
  return 1.0f - 2.0f * frcp(1.0f + fexp2(2.88539008f * x));
}

// ---- weight prep: [W;U] (K x 1024) fp32 -> per-(ch,ws)-frag bf16 order ----
// cw = ch*8+ws; col c = q*256 + ch*128 + ws*16 + (l&15)
__global__ void prep_w0(const float* __restrict__ W0, const float* __restrict__ U0,
                        __bf16* __restrict__ o) {
  const int f = blockIdx.x * 256 + threadIdx.x;  // < 393216
  const int j = f & 7, l5 = (f >> 3) & 63, g = f >> 9;
  const int kc = g % 12, q = (g / 12) & 3, cw = g / 48;
  const int k = (kc << 5) + ((l5 >> 4) << 3) + j;
  const int c = (q << 8) + ((cw >> 3) << 7) + ((cw & 7) << 4) + (l5 & 15);
  const float v = (k < 128) ? W0[(k << 10) + c] : U0[((k - 128) << 10) + c];
  o[f] = (__bf16)v;
}
__global__ void prep_w1(const float* __restrict__ W1, const float* __restrict__ U1,
                        __bf16* __restrict__ o) {
  const int f = blockIdx.x * 256 + threadIdx.x;  // < 524288
  const int j = f & 7, l5 = (f >> 3) & 63, g = f >> 9;
  const int kcx = g & 15, q = (g >> 4) & 3, cw = g >> 6;
  const int k = (kcx << 5) + ((l5 >> 4) << 3) + j;
  const int c = (q << 8) + ((cw >> 3) << 7) + ((cw & 7) << 4) + (l5 & 15);
  const float v = (k < 256) ? W1[(k << 10) + c] : U1[((k - 256) << 10) + c];
  o[f] = (__bf16)v;
}

__global__ __launch_bounds__(1024)
void lstm_fused(const float* __restrict__ traj,
                const float* __restrict__ Wemb,
                const float* __restrict__ bemb,
                const float* __restrict__ bias0,
                const float* __restrict__ bias1,
                const __bf16* __restrict__ wb0,
                const __bf16* __restrict__ wb1,
                float* __restrict__ out,
                unsigned int* flags0, unsigned int* flags1,
                char* slab0, char* slab1) {
  __shared__ __bf16 s_h0[32768];   // [r(128)][e(256)] swizzled: (r<<8)+(e^((r&7)<<3))
  __shared__ __bf16 s_h1[32768];
  __shared__ __bf16 s_ring[16384]; // 16 waves x 2 slots x 512 elems

  const int tid = threadIdx.x;
  const int wid = tid >> 6;
  const int l = tid & 63;
  const int lr = l & 15, lg = l >> 4;
  const int ws = wid & 7, rh = wid >> 3;
  const int xr = (lr & 7) << 3;
  const int b = blockIdx.x;
  const int rg = b & 63, ch = b >> 6;
  const int p = b ^ 64;           // partner block (same XCD: 64 % 8 == 0)
  const int pb = (ch ^ 1) << 7;   // partner e-half base
  const int r0 = rg << 7;         // global row base (128 rows/block)
  const int rbase = rh << 6;      // this wave's local row base
  const int e0g = (ch << 7) + (ws << 4) + (lg << 2);  // e coord within gate
  const int elb = (ws << 4) + (lg << 2);              // e_local within half

  for (int i = tid; i < 32768; i += 1024) {
    s_h0[i] = (__bf16)0.f;
    s_h1[i] = (__bf16)0.f;
  }
  __syncthreads();

  float c0s[4][4] = {};
  float c1s[4][4] = {};
  const __bf16* wp0 = wb0 + (((ch << 3) + ws) * 48) * 512 + l * 8;
  const __bf16* wp1 = wb1 + (((ch << 3) + ws) * 64) * 512 + l * 8;
  __bf16* ringp = &s_ring[wid << 10];

  auto stage = [&](int fi) {
    const __bf16* src = (fi < 48)
        ? wp0 + (((fi & 3) * 12 + (fi >> 2)) << 9)
        : wp1 + ((((fi - 48) & 3) * 16 + ((fi - 48) >> 2)) << 9);
    __builtin_amdgcn_global_load_lds(
        (const __attribute__((address_space(1))) void*)src,
        (__attribute__((address_space(3))) void*)(ringp + ((fi & 1) << 9)),
        16, 0, 0);
  };
  auto ring_read = [&](int fi) {
    return *reinterpret_cast<const bf16x8*>(ringp + ((fi & 1) << 9) + (l << 3));
  };

  stage(0);  // prime

#pragma unroll 1
  for (int t = 0; t < 32; ++t) {
    float t0v[4], t1v[4];
#pragma unroll
    for (int rt = 0; rt < 4; ++rt) {
      const int r = rbase + (rt << 4) + lr;
      const f32x2 xv = *reinterpret_cast<const f32x2*>(traj + ((r0 + r) << 6) + (t << 1));
      t0v[rt] = xv[0];
      t1v[rt] = xv[1];
    }

    {  // ---------------- layer 0: z = [x_t | h0] @ [W0;U0] + b0 ----------------
      f32x4 acc[4][4];  // [q][rt]
#pragma unroll
      for (int q = 0; q < 4; ++q) {
        const f32x4 bq = *reinterpret_cast<const f32x4*>(bias0 + (q << 8) + e0g);
#pragma unroll
        for (int rt = 0; rt < 4; ++rt) acc[q][rt] = bq;
      }
#pragma unroll
      for (int kc = 0; kc < 12; ++kc) {
        bf16x8 ia[4];
        if (kc < 4) {  // x-part: on-the-fly embed+relu (We/bemb L1-hot)
          const int kb = (kc << 5) + (lg << 3);
          const f32x4 w0a = *reinterpret_cast<const f32x4*>(Wemb + kb);
          const f32x4 w0b = *reinterpret_cast<const f32x4*>(Wemb + kb + 4);
          const f32x4 w1a = *reinterpret_cast<const f32x4*>(Wemb + 128 + kb);
          const f32x4 w1b = *reinterpret_cast<const f32x4*>(Wemb + 128 + kb + 4);
          const f32x4 bea = *reinterpret_cast<const f32x4*>(bemb + kb);
          const f32x4 beb = *reinterpret_cast<const f32x4*>(bemb + kb + 4);
#pragma unroll
          for (int rt = 0; rt < 4; ++rt) {
#pragma unroll
            for (int j = 0; j < 4; ++j) {
              const float xa = fmaf(t0v[rt], w0a[j], fmaf(t1v[rt], w1a[j], bea[j]));
              const float xb = fmaf(t0v[rt], w0b[j], fmaf(t1v[rt], w1b[j], beb[j]));
              ia[rt][j] = (__bf16)fmaxf(xa, 0.f);
              ia[rt][4 + j] = (__bf16)fmaxf(xb, 0.f);
            }
          }
        } else {  // h0-part from LDS (full 256-e K)
#pragma unroll
          for (int rt = 0; rt < 4; ++rt) {
            const int r = rbase + (rt << 4) + lr;
            ia[rt] = *reinterpret_cast<const bf16x8*>(
                &s_h0[(r << 8) + ((((kc - 4) << 5) + (lg << 3)) ^ xr)]);
          }
        }
#pragma unroll
        for (int q = 0; q < 4; ++q) {
          const int f = (kc << 2) + q;
          stage((f + 1) % 112);
          WAIT_VM1();
          __builtin_amdgcn_sched_barrier(0);
          const bf16x8 wf = ring_read(f);
#pragma unroll
          for (int rt = 0; rt < 4; ++rt) acc[q][rt] = MFMA16(wf, ia[rt], acc[q][rt]);
        }
      }
      RAW_BARRIER();  // all s_h0 reads done -> safe to overwrite own half
#pragma unroll
      for (int rt = 0; rt < 4; ++rt) {
        const int r = rbase + (rt << 4) + lr;
        bf16x4 hv;
        f32x4 hfv, cfv;
#pragma unroll
        for (int i = 0; i < 4; ++i) {
          const float cc = fsig(acc[1][rt][i]) * c0s[rt][i] +
                           fsig(acc[0][rt][i]) * ftanh(acc[2][rt][i]);
          c0s[rt][i] = cc;
          const float hh = fsig(acc[3][rt][i]) * ftanh(cc);
          hv[i] = (__bf16)hh;
          hfv[i] = hh;
          cfv[i] = cc;
        }
        *reinterpret_cast<bf16x4*>(&s_h0[(r << 8) + (e0g ^ xr)]) = hv;
        *reinterpret_cast<bf16x4*>(slab0 + b * 32768 + r * 256 + elb * 2) = hv;
        if (t == 31) {
          *reinterpret_cast<f32x4*>(out + 67108864 + ((r0 + r) << 8) + e0g) = hfv;
          *reinterpret_cast<f32x4*>(out + 69206016 + ((r0 + r) << 8) + e0g) = cfv;
        }
      }
    }

    // ---- D: pull partner h1(t-1) half into s_h1 (BEFORE posting flags0!) ----
    if (t > 0) {
      if (tid == 0) {
        while (__hip_atomic_load(&flags1[p], __ATOMIC_RELAXED,
                                 __HIP_MEMORY_SCOPE_AGENT) < (unsigned)t)
          __builtin_amdgcn_s_sleep(2);
        (void)__hip_atomic_load(&flags1[p], __ATOMIC_ACQUIRE,
                                __HIP_MEMORY_SCOPE_AGENT);
      }
      RAW_BARRIER();
      const char* sp = slab1 + p * 32768;
#pragma unroll
      for (int k = 0; k < 2; ++k) {
        const int c2 = (tid << 1) + k;
        const int rr = c2 >> 4, e8 = (c2 & 15) << 3;
        const bf16x8 v = *reinterpret_cast<const bf16x8*>(sp + rr * 256 + (e8 << 1));
        *reinterpret_cast<bf16x8*>(
            &s_h1[(rr << 8) + ((pb + e8) ^ ((rr & 7) << 3))]) = v;
      }
    }

    // ---- E: publish my h0(t) slab (drain stores first) ----
    __syncthreads();  // vmcnt(0)+lgkmcnt(0)+barrier: slab0 stores visible
    if (tid == 0)
      __hip_atomic_store(&flags0[b], (unsigned)(t + 1), __ATOMIC_RELEASE,
                         __HIP_MEMORY_SCOPE_AGENT);

    // ---- F: pull partner h0(t) half into s_h0 ----
    if (tid == 0) {
      while (__hip_atomic_load(&flags0[p], __ATOMIC_RELAXED,
                               __HIP_MEMORY_SCOPE_AGENT) < (unsigned)(t + 1))
        __builtin_amdgcn_s_sleep(2);
      (void)__hip_atomic_load(&flags0[p], __ATOMIC_ACQUIRE,
                              __HIP_MEMORY_SCOPE_AGENT);
    }
    RAW_BARRIER();
    {
      const char* sp = slab0 + p * 32768;
#pragma unroll
      for (int k = 0; k < 2; ++k) {
        const int c2 = (tid << 1) + k;
        const int rr = c2 >> 4, e8 = (c2 & 15) << 3;
        const bf16x8 v = *reinterpret_cast<const bf16x8*>(sp + rr * 256 + (e8 << 1));
        *reinterpret_cast<bf16x8*>(
            &s_h0[(rr << 8) + ((pb + e8) ^ ((rr & 7) << 3))]) = v;
      }
    }
    RAW_BARRIER();  // h0/h1 fully assembled in LDS

    {  // ---------------- layer 1: z = [h0 | h1] @ [W1;U1] + b1 ----------------
      f32x4 acc[4][4];
#pragma unroll
      for (int q = 0; q < 4; ++q) {
        const f32x4 bq = *reinterpret_cast<const f32x4*>(bias1 + (q << 8) + e0g);
#pragma unroll
        for (int rt = 0; rt < 4; ++rt) acc[q][rt] = bq;
      }
#pragma unroll
      for (int kc8 = 0; kc8 < 16; ++kc8) {
        bf16x8 ib[4];
        const __bf16* src = (kc8 < 8) ? s_h0 : s_h1;
        const int kcl = kc8 & 7;
#pragma unroll
        for (int rt = 0; rt < 4; ++rt) {
          const int r = rbase + (rt << 4) + lr;
          ib[rt] = *reinterpret_cast<const bf16x8*>(
              &src[(r << 8) + (((kcl << 5) + (lg << 3)) ^ xr)]);
        }
#pragma unroll
        for (int q = 0; q < 4; ++q) {
          const int f = 48 + (kc8 << 2) + q;
          stage((f + 1) % 112);
          WAIT_VM1();
          __builtin_amdgcn_sched_barrier(0);
          const bf16x8 wf = ring_read(f);
#pragma unroll
          for (int rt = 0; rt < 4; ++rt) acc[q][rt] = MFMA16(wf, ib[rt], acc[q][rt]);
        }
      }
      RAW_BARRIER();  // all s_h1 reads done -> safe to overwrite own half
#pragma unroll
      for (int rt = 0; rt < 4; ++rt) {
        const int r = rbase + (rt << 4) + lr;
        bf16x4 hv;
        f32x4 hfv, cfv;
#pragma unroll
        for (int i = 0; i < 4; ++i) {
          const float cc = fsig(acc[1][rt][i]) * c1s[rt][i] +
                           fsig(acc[0][rt][i]) * ftanh(acc[2][rt][i]);
          c1s[rt][i] = cc;
          const float hh = fsig(acc[3][rt][i]) * ftanh(cc);
          hv[i] = (__bf16)hh;
          hfv[i] = hh;
          cfv[i] = cc;
        }
        *reinterpret_cast<bf16x4*>(&s_h1[(r << 8) + (e0g ^ xr)]) = hv;
        *reinterpret_cast<bf16x4*>(slab1 + b * 32768 + r * 256 + elb * 2) = hv;
        if (t == 31) {
          *reinterpret_cast<f32x4*>(out + 71303168 + ((r0 + r) << 8) + e0g) = hfv;
          *reinterpret_cast<f32x4*>(out + 73400320 + ((r0 + r) << 8) + e0g) = cfv;
        }
      }
    }

    // ---- I: publish my h1(t) slab ----
    __syncthreads();
    if (tid == 0)
      __hip_atomic_store(&flags1[b], (unsigned)(t + 1), __ATOMIC_RELEASE,
                         __HIP_MEMORY_SCOPE_AGENT);

    {  // ---- J: y-write, own e-half, 64B contiguous per thread ----
      const int r = tid >> 3, g8 = tid & 7;
      const int el = g8 << 4;
      const int xr8 = (r & 7) << 3;
      const bf16x8 va = *reinterpret_cast<const bf16x8*>(
          &s_h1[(r << 8) + (((ch << 7) + el) ^ xr8)]);
      const bf16x8 vb = *reinterpret_cast<const bf16x8*>(
          &s_h1[(r << 8) + (((ch << 7) + el + 8) ^ xr8)]);
      f32x4 o0, o1, o2, o3;
#pragma unroll
      for (int i = 0; i < 4; ++i) {
        o0[i] = (float)va[i];
        o1[i] = (float)va[4 + i];
        o2[i] = (float)vb[i];
        o3[i] = (float)vb[4 + i];
      }
      float* gp = out + (((r0 + r) << 5) + t) * 256 + (ch << 7) + el;
      *reinterpret_cast<f32x4*>(gp) = o0;
      *reinterpret_cast<f32x4*>(gp + 4) = o1;
      *reinterpret_cast<f32x4*>(gp + 8) = o2;
      *reinterpret_cast<f32x4*>(gp + 12) = o3;
    }
    // next-iter D/F barriers order s_h1 partner-half writes after all J reads
  }
}

extern "C" void kernel_launch(void* const* d_in, const int* in_sizes, int n_in,
                              void* d_out, int out_size, void* d_ws, size_t ws_size,
                              hipStream_t stream) {
  const float* traj = (const float*)d_in[0];
  const float* Wemb = (const float*)d_in[1];
  const float* bemb = (const float*)d_in[2];
  const float* W0 = (const float*)d_in[3];
  const float* U0 = (const float*)d_in[4];
  const float* b0 = (const float*)d_in[5];
  const float* W1 = (const float*)d_in[6];
  const float* U1 = (const float*)d_in[7];
  const float* b1 = (const float*)d_in[8];
  float* out = (float*)d_out;

  char* base = (char*)d_ws;
  __bf16* wb0 = (__bf16*)base;                 // 786432 B
  __bf16* wb1 = (__bf16*)(base + 786432);      // 1048576 B
  unsigned int* flags0 = (unsigned int*)(base + 1835008);  // 512 B
  unsigned int* flags1 = (unsigned int*)(base + 1835520);  // 512 B
  char* slab0 = base + 1836032;                // 128*32768 = 4 MiB
  char* slab1 = base + 1836032 + 4194304;      // 4 MiB  (total ~9.8 MiB)

  hipMemsetAsync(flags0, 0, 1024, stream);  // both flag arrays
  hipLaunchKernelGGL(prep_w0, dim3(1536), dim3(256), 0, stream, W0, U0, wb0);
  hipLaunchKernelGGL(prep_w1, dim3(2048), dim3(256), 0, stream, W1, U1, wb1);
  hipLaunchKernelGGL(lstm_fused, dim3(128), dim3(1024), 0, stream,
                     traj, Wemb, bemb, b0, b1, wb0, wb1, out,
                     flags0, flags1, slab0, slab1);
}

// Round 11
// 2249.583 us; speedup vs baseline: 1.7554x; 1.7554x over previous
//
#include <hip/hip_runtime.h>
#include <hip/hip_bf16.h>

// B=8192, T=32, D_IN=2, EMB=128, H=256, 4H=1024
// r11 = r8 (2059us) + nontemporal output stores (no-allocate -> stop L2 churn
// evicting the shared 1.75MB weight set). 128 blocks x 1024 threads (16 waves);
// block owns 64 batch rows; wave wid owns cols q*256+(wid>>2)*64+(wid&3)*16+[0,16).
// Weights stream through per-wave 4-slot LDS rings via global_load_lds,
// prefetch depth 3, counted s_waitcnt vmcnt(3) (never 0 mid-stream).
// h0/h1 single-buffered; raw s_barrier with lgkmcnt-only waits.

typedef __attribute__((ext_vector_type(8))) __bf16 bf16x8;
typedef __attribute__((ext_vector_type(4))) __bf16 bf16x4;
typedef __attribute__((ext_vector_type(4))) float f32x4;
typedef __attribute__((ext_vector_type(2))) float f32x2;

#define MFMA16(a, b, c) __builtin_amdgcn_mfma_f32_16x16x32_bf16(a, b, c, 0, 0, 0)

// s_waitcnt imm (gfx9): vmcnt[3:0]|[15:14], expcnt[6:4], lgkm[11:8]
#define WAIT_VM3() __builtin_amdgcn_s_waitcnt(0xF73)     // vmcnt(3), others no-wait
#define WAIT_LGKM0() __builtin_amdgcn_s_waitcnt(0xC07F)  // lgkmcnt(0), others no-wait
#define RAW_BARRIER()                  \
  do {                                 \
    WAIT_LGKM0();                      \
    __builtin_amdgcn_sched_barrier(0); \
    __builtin_amdgcn_s_barrier();      \
  } while (0)

__device__ __forceinline__ float fexp2(float x) {
#if __has_builtin(__builtin_amdgcn_exp2f)
  return __builtin_amdgcn_exp2f(x);
#else
  return exp2f(x);
#endif
}
__device__ __forceinline__ float frcp(float x) {
#if __has_builtin(__builtin_amdgcn_rcpf)
  return __builtin_amdgcn_rcpf(x);
#else
  return 1.0f / x;
#endif
}
__device__ __forceinline__ float fsig(float x) {
  return frcp(1.0f + fexp2(-1.44269504f * x));
}
__device__ __forceinline__ float ftanh(float x) {
  return 1.0f - 2.0f * frcp(1.0f + fexp2(2.88539008f * x));
}

// ---- weight prep: swizzle [W;U] (K x 1024) fp32 -> per-frag bf16 order ----
__global__ void prep_w0(const float* __restrict__ W0, const float* __restrict__ U0,
                        __bf16* __restrict__ o) {
  const int f = blockIdx.x * 256 + threadIdx.x;  // < 393216
  const int j = f & 7, l5 = (f >> 3) & 63, g = f >> 9;
  const int kc = g % 12, q = (g / 12) & 3, wid = g / 48;
  const int k = (kc << 5) + ((l5 >> 4) << 3) + j;
  const int c = (q << 8) + ((wid >> 2) << 6) + ((wid & 3) << 4) + (l5 & 15);
  const float v = (k < 128) ? W0[(k << 10) + c] : U0[((k - 128) << 10) + c];
  o[f] = (__bf16)v;
}
__global__ void prep_w1(const float* __restrict__ W1, const float* __restrict__ U1,
                        __bf16* __restrict__ o) {
  const int f = blockIdx.x * 256 + threadIdx.x;  // < 524288
  const int j = f & 7, l5 = (f >> 3) & 63, g = f >> 9;
  const int kcx = g & 15, q = (g >> 4) & 3, wid = g >> 6;
  const int k = (kcx << 5) + ((l5 >> 4) << 3) + j;
  const int c = (q << 8) + ((wid >> 2) << 6) + ((wid & 3) << 4) + (l5 & 15);
  const float v = (k < 256) ? W1[(k << 10) + c] : U1[((k - 256) << 10) + c];
  o[f] = (__bf16)v;
}

__global__ __launch_bounds__(1024)
void lstm_fused(const float* __restrict__ traj,
                const float* __restrict__ Wemb,
                const float* __restrict__ bemb,
                const float* __restrict__ bias0,
                const float* __restrict__ bias1,
                const __bf16* __restrict__ wb0,
                const __bf16* __restrict__ wb1,
                float* __restrict__ out) {
  __shared__ float s_We[384];       // We[0][:], We[1][:], be[:]
  __shared__ float s_b[2][1024];    // bias in (ct, cc) order
  __shared__ float s_traj[4096];    // [t][r][d]
  __shared__ __bf16 s_h0[16384];    // single buf: [r*256 + (e ^ ((r&7)<<3))]
  __shared__ __bf16 s_h1[16384];
  __shared__ __bf16 s_ring[32768];  // 16 waves x 4 slots x 512 elems (1KB)

  const int tid = threadIdx.x;
  const int wid = tid >> 6;
  const int l = tid & 63;
  const int lr = l & 15, lg = l >> 4;
  const int w = wid >> 2, s4 = wid & 3;
  const int xr = (lr & 7) << 3;
  const int r0 = blockIdx.x << 6;

  if (tid < 384) s_We[tid] = (tid < 256) ? Wemb[tid] : bemb[tid - 256];
  {
    const int ct = tid >> 4, cc = tid & 15;
    const int wd = ct >> 2, q = ct & 3;
    const int col = (q << 8) + ((wd >> 2) << 6) + ((wd & 3) << 4) + cc;
    s_b[0][tid] = bias0[col];
    s_b[1][tid] = bias1[col];
  }
  for (int i = tid; i < 4096; i += 1024) {
    const int r = i >> 6, tt = (i >> 1) & 31, d = i & 1;
    s_traj[(tt << 7) + (r << 1) + d] = traj[(r0 << 6) + i];
  }
  for (int i = tid; i < 16384; i += 1024) {
    s_h0[i] = (__bf16)0.f;
    s_h1[i] = (__bf16)0.f;
  }
  __syncthreads();

  float c0s[4][4] = {};
  float c1s[4][4] = {};
  const __bf16* wp0 = wb0 + wid * 48 * 512 + l * 8;
  const __bf16* wp1 = wb1 + wid * 64 * 512 + l * 8;
  const int e0 = (w << 6) + (s4 << 4) + (lg << 2);
  __bf16* ringp = &s_ring[wid << 11];  // 4 slots x 512 elems per wave

  auto stage = [&](int fi) {
    const __bf16* src = (fi < 48)
        ? wp0 + (((fi & 3) * 12 + (fi >> 2)) << 9)
        : wp1 + ((((fi - 48) & 3) * 16 + ((fi - 48) >> 2)) << 9);
    __builtin_amdgcn_global_load_lds(
        (const __attribute__((address_space(1))) void*)src,
        (__attribute__((address_space(3))) void*)(ringp + ((fi & 3) << 9)),
        16, 0, 0);
  };
  auto ring_read = [&](int fi) {
    return *reinterpret_cast<const bf16x8*>(ringp + ((fi & 3) << 9) + (l << 3));
  };

  // prime the ring 3 deep
  stage(0); stage(1); stage(2);

#pragma unroll 1
  for (int t = 0; t < 32; ++t) {
    {  // ---------------- layer 0: z = [x_t | h0] @ [W0;U0] + b0 ----------------
      f32x4 acc[4][4];  // [q][rt]
#pragma unroll
      for (int q = 0; q < 4; ++q) {
        const f32x4 b = *reinterpret_cast<const f32x4*>(
            &s_b[0][(((wid << 2) + q) << 4) + (lg << 2)]);
#pragma unroll
        for (int rt = 0; rt < 4; ++rt) acc[q][rt] = b;
      }
      float t0v[4], t1v[4];
#pragma unroll
      for (int rt = 0; rt < 4; ++rt) {
        const int r = (rt << 4) + lr;
        t0v[rt] = s_traj[(t << 7) + (r << 1)];
        t1v[rt] = s_traj[(t << 7) + (r << 1) + 1];
      }
#pragma unroll
      for (int kc = 0; kc < 12; ++kc) {
        bf16x8 ia[4];
        if (kc < 4) {  // x-part computed on the fly
#pragma unroll
          for (int rt = 0; rt < 4; ++rt) {
#pragma unroll
            for (int j = 0; j < 8; ++j) {
              const int k = (kc << 5) + (lg << 3) + j;
              const float x = fmaf(t0v[rt], s_We[k],
                                   fmaf(t1v[rt], s_We[128 + k], s_We[256 + k]));
              ia[rt][j] = (__bf16)fmaxf(x, 0.f);
            }
          }
        } else {  // h0 part from LDS
#pragma unroll
          for (int rt = 0; rt < 4; ++rt) {
            const int r = (rt << 4) + lr;
            ia[rt] = *reinterpret_cast<const bf16x8*>(
                &s_h0[(r << 8) + ((((kc - 4) << 5) + (lg << 3)) ^ xr)]);
          }
        }
#pragma unroll
        for (int q = 0; q < 4; ++q) {
          const int f = (kc << 2) + q;
          stage((f + 3) % 112);  // wraps into next step's frags at the tail
          WAIT_VM3();
          __builtin_amdgcn_sched_barrier(0);
          const bf16x8 wf = ring_read(f);
#pragma unroll
          for (int rt = 0; rt < 4; ++rt) acc[q][rt] = MFMA16(wf, ia[rt], acc[q][rt]);
        }
      }
      RAW_BARRIER();  // all s_h0 reads done -> safe to overwrite in place
#pragma unroll
      for (int rt = 0; rt < 4; ++rt) {
        const int r = (rt << 4) + lr;
        bf16x4 hv;
        f32x4 cfv;
#pragma unroll
        for (int i = 0; i < 4; ++i) {
          const float cc = fsig(acc[1][rt][i]) * c0s[rt][i] +
                           fsig(acc[0][rt][i]) * ftanh(acc[2][rt][i]);
          c0s[rt][i] = cc;
          const float hh = fsig(acc[3][rt][i]) * ftanh(cc);
          hv[i] = (__bf16)hh;
          cfv[i] = cc;
        }
        *reinterpret_cast<bf16x4*>(&s_h0[(r << 8) + (e0 ^ xr)]) = hv;
        if (t == 31) {  // c0 final
          __builtin_nontemporal_store(
              cfv, reinterpret_cast<f32x4*>(out + 69206016 + ((r0 + r) << 8) + e0));
        }
      }
      RAW_BARRIER();  // h0(t) complete in LDS
    }

    {  // ---------------- layer 1: z = [h0_new | h1] @ [W1;U1] + b1 ----------------
      f32x4 acc[4][4];
#pragma unroll
      for (int q = 0; q < 4; ++q) {
        const f32x4 b = *reinterpret_cast<const f32x4*>(
            &s_b[1][(((wid << 2) + q) << 4) + (lg << 2)]);
#pragma unroll
        for (int rt = 0; rt < 4; ++rt) acc[q][rt] = b;
      }
#pragma unroll
      for (int kc8 = 0; kc8 < 16; ++kc8) {
        bf16x8 ib[4];
        const __bf16* src = (kc8 < 8) ? s_h0 : s_h1;
        const int kcl = kc8 & 7;
#pragma unroll
        for (int rt = 0; rt < 4; ++rt) {
          const int r = (rt << 4) + lr;
          ib[rt] = *reinterpret_cast<const bf16x8*>(
              &src[(r << 8) + (((kcl << 5) + (lg << 3)) ^ xr)]);
        }
#pragma unroll
        for (int q = 0; q < 4; ++q) {
          const int f = 48 + (kc8 << 2) + q;
          stage((f + 3) % 112);
          WAIT_VM3();
          __builtin_amdgcn_sched_barrier(0);
          const bf16x8 wf = ring_read(f);
#pragma unroll
          for (int rt = 0; rt < 4; ++rt) acc[q][rt] = MFMA16(wf, ib[rt], acc[q][rt]);
        }
      }
      RAW_BARRIER();  // all s_h1 reads done -> safe to overwrite in place
#pragma unroll
      for (int rt = 0; rt < 4; ++rt) {
        const int r = (rt << 4) + lr;
        bf16x4 hv;
        f32x4 cfv;
#pragma unroll
        for (int i = 0; i < 4; ++i) {
          const float cc = fsig(acc[1][rt][i]) * c1s[rt][i] +
                           fsig(acc[0][rt][i]) * ftanh(acc[2][rt][i]);
          c1s[rt][i] = cc;
          const float hh = fsig(acc[3][rt][i]) * ftanh(cc);
          hv[i] = (__bf16)hh;
          cfv[i] = cc;
        }
        *reinterpret_cast<bf16x4*>(&s_h1[(r << 8) + (e0 ^ xr)]) = hv;
        if (t == 31) {  // c1 final
          __builtin_nontemporal_store(
              cfv, reinterpret_cast<f32x4*>(out + 73400320 + ((r0 + r) << 8) + e0));
        }
      }
      RAW_BARRIER();  // h1(t) complete in LDS
    }

    {  // ---- y write: nontemporal full-cacheline stores (64 x 16B = 1KB/row) ----
#pragma unroll
      for (int j = 0; j < 4; ++j) {
        const int row = (wid << 2) + j;
        const int xw = (row & 7) << 3;
        const bf16x4 a =
            *reinterpret_cast<const bf16x4*>(&s_h1[(row << 8) + ((l << 2) ^ xw)]);
        f32x4 v;
#pragma unroll
        for (int i = 0; i < 4; ++i) v[i] = (float)a[i];
        __builtin_nontemporal_store(
            v, reinterpret_cast<f32x4*>(out + ((((r0 + row) << 5) + t) << 8) + (l << 2)));
        if (t == 31) {
          __builtin_nontemporal_store(
              v, reinterpret_cast<f32x4*>(out + 71303168 + ((r0 + row) << 8) + (l << 2)));
          const bf16x4 a0 = *reinterpret_cast<const bf16x4*>(
              &s_h0[(row << 8) + ((l << 2) ^ xw)]);
          f32x4 v0;
#pragma unroll
          for (int i = 0; i < 4; ++i) v0[i] = (float)a0[i];
          __builtin_nontemporal_store(
              v0, reinterpret_cast<f32x4*>(out + 67108864 + ((r0 + row) << 8) + (l << 2)));
        }
      }
      // stores sit in the vmcnt queue ahead of the next stages; the next
      // WAIT_VM3 conservatively drains them (small boundary bubble, correct).
    }
  }
}

extern "C" void kernel_launch(void* const* d_in, const int* in_sizes, int n_in,
                              void* d_out, int out_size, void* d_ws, size_t ws_size,
                              hipStream_t stream) {
  const float* traj = (const float*)d_in[0];
  const float* Wemb = (const float*)d_in[1];
  const float* bemb = (const float*)d_in[2];
  const float* W0 = (const float*)d_in[3];
  const float* U0 = (const float*)d_in[4];
  const float* b0 = (const float*)d_in[5];
  const float* W1 = (const float*)d_in[6];
  const float* U1 = (const float*)d_in[7];
  const float* b1 = (const float*)d_in[8];
  float* out = (float*)d_out;

  __bf16* wb0 = (__bf16*)d_ws;  // 393216 elems = 768 KB
  __bf16* wb1 = wb0 + 393216;   // 524288 elems = 1 MB

  hipLaunchKernelGGL(prep_w0, dim3(1536), dim3(256), 0, stream, W0, U0, wb0);
  hipLaunchKernelGGL(prep_w1, dim3(2048), dim3(256), 0, stream, W1, U1, wb1);
  hipLaunchKernelGGL(lstm_fused, dim3(128), dim3(1024), 0, stream,
                     traj, Wemb, bemb, b0, b1, wb0, wb1, out);
}

// Round 12
// 1379.045 us; speedup vs baseline: 2.8635x; 1.6313x over previous
//
#include <hip/hip_runtime.h>
#include <hip/hip_bf16.h>

// B=8192, T=32, D_IN=2, EMB=128, H=256, 4H=1024
// r12: two-phase layer split. l0_pass streams only [W0;U0] (0.75MB, L2-resident
// per XCD), writes h0[t] to a 134MB bf16 slab (full-line 512B stores).
// l1_pass streams only [W1;U1] (1MB, L2-resident), ingests h0(t) via
// global_load_lds with pre-swizzled per-lane source addresses.
// 256 blocks x 1024 threads (16 waves), 32 rows/block; r8 ring: 4 slots,
// depth 3, counted vmcnt(3), wrap across steps. Fallback: r11 fused kernel.

typedef __attribute__((ext_vector_type(8))) __bf16 bf16x8;
typedef __attribute__((ext_vector_type(4))) __bf16 bf16x4;
typedef __attribute__((ext_vector_type(4))) float f32x4;

#define MFMA16(a, b, c) __builtin_amdgcn_mfma_f32_16x16x32_bf16(a, b, c, 0, 0, 0)

// s_waitcnt imm (gfx9): vmcnt[3:0]|[15:14], expcnt[6:4], lgkm[11:8]
#define WAIT_VM3() __builtin_amdgcn_s_waitcnt(0xF73)
#define WAIT_LGKM0() __builtin_amdgcn_s_waitcnt(0xC07F)
#define RAW_BARRIER()                  \
  do {                                 \
    WAIT_LGKM0();                      \
    __builtin_amdgcn_sched_barrier(0); \
    __builtin_amdgcn_s_barrier();      \
  } while (0)

__device__ __forceinline__ float fexp2(float x) {
#if __has_builtin(__builtin_amdgcn_exp2f)
  return __builtin_amdgcn_exp2f(x);
#else
  return exp2f(x);
#endif
}
__device__ __forceinline__ float frcp(float x) {
#if __has_builtin(__builtin_amdgcn_rcpf)
  return __builtin_amdgcn_rcpf(x);
#else
  return 1.0f / x;
#endif
}
__device__ __forceinline__ float fsig(float x) {
  return frcp(1.0f + fexp2(-1.44269504f * x));
}
__device__ __forceinline__ float ftanh(float x) {
  return 1.0f - 2.0f * frcp(1.0f + fexp2(2.88539008f * x));
}

// ---- weight prep: swizzle [W;U] (K x 1024) fp32 -> per-frag bf16 order ----
__global__ void prep_w0(const float* __restrict__ W0, const float* __restrict__ U0,
                        __bf16* __restrict__ o) {
  const int f = blockIdx.x * 256 + threadIdx.x;  // < 393216
  const int j = f & 7, l5 = (f >> 3) & 63, g = f >> 9;
  const int kc = g % 12, q = (g / 12) & 3, wid = g / 48;
  const int k = (kc << 5) + ((l5 >> 4) << 3) + j;
  const int c = (q << 8) + ((wid >> 2) << 6) + ((wid & 3) << 4) + (l5 & 15);
  const float v = (k < 128) ? W0[(k << 10) + c] : U0[((k - 128) << 10) + c];
  o[f] = (__bf16)v;
}
__global__ void prep_w1(const float* __restrict__ W1, const float* __restrict__ U1,
                        __bf16* __restrict__ o) {
  const int f = blockIdx.x * 256 + threadIdx.x;  // < 524288
  const int j = f & 7, l5 = (f >> 3) & 63, g = f >> 9;
  const int kcx = g & 15, q = (g >> 4) & 3, wid = g >> 6;
  const int k = (kcx << 5) + ((l5 >> 4) << 3) + j;
  const int c = (q << 8) + ((wid >> 2) << 6) + ((wid & 3) << 4) + (l5 & 15);
  const float v = (k < 256) ? W1[(k << 10) + c] : U1[((k - 256) << 10) + c];
  o[f] = (__bf16)v;
}

// ============================ phase 0: layer 0 =============================
__global__ __launch_bounds__(1024)
void lstm_l0(const float* __restrict__ traj,
             const float* __restrict__ Wemb,
             const float* __restrict__ bemb,
             const float* __restrict__ bias0,
             const __bf16* __restrict__ wb0,
             float* __restrict__ out,
             __bf16* __restrict__ slab) {
  __shared__ float s_We[384];
  __shared__ float s_b[1024];
  __shared__ float s_traj[2048];    // [t][r][d]: t*64 + r*2 + d (32 rows)
  __shared__ __bf16 s_h0[8192];     // 32 rows x 256, swizzled
  __shared__ __bf16 s_ring[32768];  // 16 waves x 4 slots x 512

  const int tid = threadIdx.x;
  const int wid = tid >> 6;
  const int l = tid & 63;
  const int lr = l & 15, lg = l >> 4;
  const int w = wid >> 2, s4 = wid & 3;
  const int xr = (lr & 7) << 3;
  const int r0 = blockIdx.x << 5;
  const int e0 = (w << 6) + (s4 << 4) + (lg << 2);

  if (tid < 384) s_We[tid] = (tid < 256) ? Wemb[tid] : bemb[tid - 256];
  {
    const int ct = tid >> 4, cc = tid & 15;
    const int wd = ct >> 2, q = ct & 3;
    const int col = (q << 8) + ((wd >> 2) << 6) + ((wd & 3) << 4) + cc;
    s_b[tid] = bias0[col];
  }
  for (int i = tid; i < 2048; i += 1024) {
    const int r = i >> 6, tt = (i >> 1) & 31, d = i & 1;
    s_traj[(tt << 6) + (r << 1) + d] = traj[(r0 << 6) + i];
  }
  for (int i = tid; i < 8192; i += 1024) s_h0[i] = (__bf16)0.f;
  __syncthreads();

  float c0s[2][4] = {};
  const __bf16* wp0 = wb0 + wid * 48 * 512 + l * 8;
  __bf16* ringp = &s_ring[wid << 11];

  auto stage = [&](int cf) {  // cf = kc*4+q in [0,48)
    const __bf16* src = wp0 + (((cf & 3) * 12 + (cf >> 2)) << 9);
    __builtin_amdgcn_global_load_lds(
        (const __attribute__((address_space(1))) void*)src,
        (__attribute__((address_space(3))) void*)(ringp + ((cf & 3) << 9)),
        16, 0, 0);
  };
  auto ring_read = [&](int cf) {
    return *reinterpret_cast<const bf16x8*>(ringp + ((cf & 3) << 9) + (l << 3));
  };

  stage(0); stage(1); stage(2);

#pragma unroll 1
  for (int t = 0; t < 32; ++t) {
    f32x4 acc[4][2];
#pragma unroll
    for (int q = 0; q < 4; ++q) {
      const f32x4 b =
          *reinterpret_cast<const f32x4*>(&s_b[(((wid << 2) + q) << 4) + (lg << 2)]);
      acc[q][0] = b;
      acc[q][1] = b;
    }
    float t0v[2], t1v[2];
#pragma unroll
    for (int rt = 0; rt < 2; ++rt) {
      const int r = (rt << 4) + lr;
      t0v[rt] = s_traj[(t << 6) + (r << 1)];
      t1v[rt] = s_traj[(t << 6) + (r << 1) + 1];
    }
#pragma unroll
    for (int kc = 0; kc < 12; ++kc) {
      bf16x8 ia[2];
      if (kc < 4) {  // x-part on the fly
#pragma unroll
        for (int rt = 0; rt < 2; ++rt) {
#pragma unroll
          for (int j = 0; j < 8; ++j) {
            const int k = (kc << 5) + (lg << 3) + j;
            const float x = fmaf(t0v[rt], s_We[k],
                                 fmaf(t1v[rt], s_We[128 + k], s_We[256 + k]));
            ia[rt][j] = (__bf16)fmaxf(x, 0.f);
          }
        }
      } else {
#pragma unroll
        for (int rt = 0; rt < 2; ++rt) {
          const int r = (rt << 4) + lr;
          ia[rt] = *reinterpret_cast<const bf16x8*>(
              &s_h0[(r << 8) + ((((kc - 4) << 5) + (lg << 3)) ^ xr)]);
        }
      }
#pragma unroll
      for (int q = 0; q < 4; ++q) {
        const int cf = (kc << 2) + q;
        stage((cf + 3) % 48);
        WAIT_VM3();
        __builtin_amdgcn_sched_barrier(0);
        const bf16x8 wf = ring_read(cf);
        acc[q][0] = MFMA16(wf, ia[0], acc[q][0]);
        acc[q][1] = MFMA16(wf, ia[1], acc[q][1]);
      }
    }
    RAW_BARRIER();  // all s_h0 reads done
#pragma unroll
    for (int rt = 0; rt < 2; ++rt) {
      const int r = (rt << 4) + lr;
      bf16x4 hv;
      f32x4 cfv;
#pragma unroll
      for (int i = 0; i < 4; ++i) {
        const float cc = fsig(acc[1][rt][i]) * c0s[rt][i] +
                         fsig(acc[0][rt][i]) * ftanh(acc[2][rt][i]);
        c0s[rt][i] = cc;
        hv[i] = (__bf16)(fsig(acc[3][rt][i]) * ftanh(cc));
        cfv[i] = cc;
      }
      *reinterpret_cast<bf16x4*>(&s_h0[(r << 8) + (e0 ^ xr)]) = hv;
      if (t == 31) {  // c0 final
        __builtin_nontemporal_store(
            cfv, reinterpret_cast<f32x4*>(out + 69206016 + ((r0 + r) << 8) + e0));
      }
    }
    RAW_BARRIER();  // h0(t) complete in LDS

    // slab copy: wave writes rows 2wid, 2wid+1 as full 512B lines (de-swizzled)
#pragma unroll
    for (int rr = 0; rr < 2; ++rr) {
      const int row = (wid << 1) + rr;
      const bf16x4 hv4 = *reinterpret_cast<const bf16x4*>(
          &s_h0[(row << 8) + ((l << 2) ^ ((row & 7) << 3))]);
      *reinterpret_cast<bf16x4*>(
          slab + ((size_t)(t * 8192 + r0 + row) << 8) + (l << 2)) = hv4;
      if (t == 31) {  // h0 final (fp32, full-line)
        f32x4 v;
#pragma unroll
        for (int i = 0; i < 4; ++i) v[i] = (float)hv4[i];
        *reinterpret_cast<f32x4*>(out + 67108864 + ((r0 + row) << 8) + (l << 2)) = v;
      }
    }
    // no barrier: s_h0 next written at t+1 epilogue, behind its RAW_BARRIERs
  }
}

// ============================ phase 1: layer 1 =============================
__global__ __launch_bounds__(1024)
void lstm_l1(const float* __restrict__ bias1,
             const __bf16* __restrict__ wb1,
             const __bf16* __restrict__ slab,
             float* __restrict__ out) {
  __shared__ float s_b[1024];
  __shared__ __bf16 s_h0[8192];     // staged h0(t), swizzled
  __shared__ __bf16 s_h1[8192];
  __shared__ __bf16 s_ring[32768];

  const int tid = threadIdx.x;
  const int wid = tid >> 6;
  const int l = tid & 63;
  const int lr = l & 15, lg = l >> 4;
  const int w = wid >> 2, s4 = wid & 3;
  const int xr = (lr & 7) << 3;
  const int r0 = blockIdx.x << 5;
  const int e0 = (w << 6) + (s4 << 4) + (lg << 2);

  {
    const int ct = tid >> 4, cc = tid & 15;
    const int wd = ct >> 2, q = ct & 3;
    const int col = (q << 8) + ((wd >> 2) << 6) + ((wd & 3) << 4) + cc;
    s_b[tid] = bias1[col];
  }
  for (int i = tid; i < 8192; i += 1024) s_h1[i] = (__bf16)0.f;
  __syncthreads();

  float c1s[2][4] = {};
  const __bf16* wp1 = wb1 + wid * 64 * 512 + l * 8;
  __bf16* ringp = &s_ring[wid << 11];

  // consumption order: it8 0..7 -> kcx 8..15 (U1/h1 part), it8 8..15 -> kcx 0..7
  auto stage = [&](int cf) {  // cf = it8*4+q in [0,64)
    const int it8 = (cf >> 2) & 15, q = cf & 3;
    const int kcx = it8 ^ 8;
    const __bf16* src = wp1 + (((q << 4) + kcx) << 9);
    __builtin_amdgcn_global_load_lds(
        (const __attribute__((address_space(1))) void*)src,
        (__attribute__((address_space(3))) void*)(ringp + ((cf & 3) << 9)),
        16, 0, 0);
  };
  auto ring_read = [&](int cf) {
    return *reinterpret_cast<const bf16x8*>(ringp + ((cf & 3) << 9) + (l << 3));
  };

  // ingest addressing: wave ingests local rows 2wid, 2wid+1 (1KB = one gload_lds)
  const int irow = (wid << 1) + (l >> 5);
  const int iwb = (l & 31) << 4;  // within-row byte
  const size_t ioff =
      ((size_t)(r0 + irow) << 8) + ((iwb ^ ((irow & 7) << 4)) >> 1);  // elems

  stage(0); stage(1); stage(2);

#pragma unroll 1
  for (int t = 0; t < 32; ++t) {
    // ingest h0(t): pre-swizzled source -> linear LDS dest
    __builtin_amdgcn_global_load_lds(
        (const __attribute__((address_space(1))) void*)(slab + ((size_t)t * 8192 << 8) + ioff),
        (__attribute__((address_space(3))) void*)(s_h0 + (wid << 9)),
        16, 0, 0);

    f32x4 acc[4][2];
#pragma unroll
    for (int q = 0; q < 4; ++q) {
      const f32x4 b =
          *reinterpret_cast<const f32x4*>(&s_b[(((wid << 2) + q) << 4) + (lg << 2)]);
      acc[q][0] = b;
      acc[q][1] = b;
    }
    // ---- h1 part (kcx 8..15) ----
#pragma unroll
    for (int it8 = 0; it8 < 8; ++it8) {
      bf16x8 ib[2];
#pragma unroll
      for (int rt = 0; rt < 2; ++rt) {
        const int r = (rt << 4) + lr;
        ib[rt] = *reinterpret_cast<const bf16x8*>(
            &s_h1[(r << 8) + (((it8 << 5) + (lg << 3)) ^ xr)]);
      }
#pragma unroll
      for (int q = 0; q < 4; ++q) {
        const int cf = (it8 << 2) + q;
        stage((cf + 3) % 64);
        WAIT_VM3();
        __builtin_amdgcn_sched_barrier(0);
        const bf16x8 wf = ring_read(cf);
        acc[q][0] = MFMA16(wf, ib[0], acc[q][0]);
        acc[q][1] = MFMA16(wf, ib[1], acc[q][1]);
      }
    }
    // all waves issued >=32 counted waits after their ingest -> own DMA retired;
    // barrier publishes every wave's ingested rows before any h0 read.
    RAW_BARRIER();
    // ---- h0 part (kcx 0..7) ----
#pragma unroll
    for (int it8 = 8; it8 < 16; ++it8) {
      const int kcl = it8 - 8;
      bf16x8 ib[2];
#pragma unroll
      for (int rt = 0; rt < 2; ++rt) {
        const int r = (rt << 4) + lr;
        ib[rt] = *reinterpret_cast<const bf16x8*>(
            &s_h0[(r << 8) + (((kcl << 5) + (lg << 3)) ^ xr)]);
      }
#pragma unroll
      for (int q = 0; q < 4; ++q) {
        const int cf = (it8 << 2) + q;
        stage((cf + 3) % 64);
        WAIT_VM3();
        __builtin_amdgcn_sched_barrier(0);
        const bf16x8 wf = ring_read(cf);
        acc[q][0] = MFMA16(wf, ib[0], acc[q][0]);
        acc[q][1] = MFMA16(wf, ib[1], acc[q][1]);
      }
    }
    RAW_BARRIER();  // all s_h1 reads done
#pragma unroll
    for (int rt = 0; rt < 2; ++rt) {
      const int r = (rt << 4) + lr;
      bf16x4 hv;
      f32x4 cfv;
#pragma unroll
      for (int i = 0; i < 4; ++i) {
        const float cc = fsig(acc[1][rt][i]) * c1s[rt][i] +
                         fsig(acc[0][rt][i]) * ftanh(acc[2][rt][i]);
        c1s[rt][i] = cc;
        hv[i] = (__bf16)(fsig(acc[3][rt][i]) * ftanh(cc));
        cfv[i] = cc;
      }
      *reinterpret_cast<bf16x4*>(&s_h1[(r << 8) + (e0 ^ xr)]) = hv;
      if (t == 31) {  // c1 final
        __builtin_nontemporal_store(
            cfv, reinterpret_cast<f32x4*>(out + 73400320 + ((r0 + r) << 8) + e0));
      }
    }
    RAW_BARRIER();  // h1(t) complete in LDS

    // y write: wave writes rows 2wid, 2wid+1, one full 1KB row per instruction
#pragma unroll
    for (int j = 0; j < 2; ++j) {
      const int row = (wid << 1) + j;
      const int xw = (row & 7) << 3;
      const bf16x4 a =
          *reinterpret_cast<const bf16x4*>(&s_h1[(row << 8) + ((l << 2) ^ xw)]);
      f32x4 v;
#pragma unroll
      for (int i = 0; i < 4; ++i) v[i] = (float)a[i];
      *reinterpret_cast<f32x4*>(out + ((((r0 + row) << 5) + t) << 8) + (l << 2)) = v;
      if (t == 31) {  // h1 final = y[:,31,:]
        *reinterpret_cast<f32x4*>(out + 71303168 + ((r0 + row) << 8) + (l << 2)) = v;
      }
    }
  }
}

// ======================= fallback: r11 fused kernel ========================
__global__ __launch_bounds__(1024)
void lstm_fused(const float* __restrict__ traj,
                const float* __restrict__ Wemb,
                const float* __restrict__ bemb,
                const float* __restrict__ bias0,
                const float* __restrict__ bias1,
                const __bf16* __restrict__ wb0,
                const __bf16* __restrict__ wb1,
                float* __restrict__ out) {
  __shared__ float s_We[384];
  __shared__ float s_b[2][1024];
  __shared__ float s_traj[4096];
  __shared__ __bf16 s_h0[16384];
  __shared__ __bf16 s_h1[16384];
  __shared__ __bf16 s_ring[32768];

  const int tid = threadIdx.x;
  const int wid = tid >> 6;
  const int l = tid & 63;
  const int lr = l & 15, lg = l >> 4;
  const int w = wid >> 2, s4 = wid & 3;
  const int xr = (lr & 7) << 3;
  const int r0 = blockIdx.x << 6;

  if (tid < 384) s_We[tid] = (tid < 256) ? Wemb[tid] : bemb[tid - 256];
  {
    const int ct = tid >> 4, cc = tid & 15;
    const int wd = ct >> 2, q = ct & 3;
    const int col = (q << 8) + ((wd >> 2) << 6) + ((wd & 3) << 4) + cc;
    s_b[0][tid] = bias0[col];
    s_b[1][tid] = bias1[col];
  }
  for (int i = tid; i < 4096; i += 1024) {
    const int r = i >> 6, tt = (i >> 1) & 31, d = i & 1;
    s_traj[(tt << 7) + (r << 1) + d] = traj[(r0 << 6) + i];
  }
  for (int i = tid; i < 16384; i += 1024) {
    s_h0[i] = (__bf16)0.f;
    s_h1[i] = (__bf16)0.f;
  }
  __syncthreads();

  float c0s[4][4] = {};
  float c1s[4][4] = {};
  const __bf16* wp0 = wb0 + wid * 48 * 512 + l * 8;
  const __bf16* wp1 = wb1 + wid * 64 * 512 + l * 8;
  const int e0 = (w << 6) + (s4 << 4) + (lg << 2);
  __bf16* ringp = &s_ring[wid << 11];

  auto stage = [&](int fi) {
    const __bf16* src = (fi < 48)
        ? wp0 + (((fi & 3) * 12 + (fi >> 2)) << 9)
        : wp1 + ((((fi - 48) & 3) * 16 + ((fi - 48) >> 2)) << 9);
    __builtin_amdgcn_global_load_lds(
        (const __attribute__((address_space(1))) void*)src,
        (__attribute__((address_space(3))) void*)(ringp + ((fi & 3) << 9)),
        16, 0, 0);
  };
  auto ring_read = [&](int fi) {
    return *reinterpret_cast<const bf16x8*>(ringp + ((fi & 3) << 9) + (l << 3));
  };

  stage(0); stage(1); stage(2);

#pragma unroll 1
  for (int t = 0; t < 32; ++t) {
    {
      f32x4 acc[4][4];
#pragma unroll
      for (int q = 0; q < 4; ++q) {
        const f32x4 b = *reinterpret_cast<const f32x4*>(
            &s_b[0][(((wid << 2) + q) << 4) + (lg << 2)]);
#pragma unroll
        for (int rt = 0; rt < 4; ++rt) acc[q][rt] = b;
      }
      float t0v[4], t1v[4];
#pragma unroll
      for (int rt = 0; rt < 4; ++rt) {
        const int r = (rt << 4) + lr;
        t0v[rt] = s_traj[(t << 7) + (r << 1)];
        t1v[rt] = s_traj[(t << 7) + (r << 1) + 1];
      }
#pragma unroll
      for (int kc = 0; kc < 12; ++kc) {
        bf16x8 ia[4];
        if (kc < 4) {
#pragma unroll
          for (int rt = 0; rt < 4; ++rt) {
#pragma unroll
            for (int j = 0; j < 8; ++j) {
              const int k = (kc << 5) + (lg << 3) + j;
              const float x = fmaf(t0v[rt], s_We[k],
                                   fmaf(t1v[rt], s_We[128 + k], s_We[256 + k]));
              ia[rt][j] = (__bf16)fmaxf(x, 0.f);
            }
          }
        } else {
#pragma unroll
          for (int rt = 0; rt < 4; ++rt) {
            const int r = (rt << 4) + lr;
            ia[rt] = *reinterpret_cast<const bf16x8*>(
                &s_h0[(r << 8) + ((((kc - 4) << 5) + (lg << 3)) ^ xr)]);
          }
        }
#pragma unroll
        for (int q = 0; q < 4; ++q) {
          const int f = (kc << 2) + q;
          stage((f + 3) % 112);
          WAIT_VM3();
          __builtin_amdgcn_sched_barrier(0);
          const bf16x8 wf = ring_read(f);
#pragma unroll
          for (int rt = 0; rt < 4; ++rt) acc[q][rt] = MFMA16(wf, ia[rt], acc[q][rt]);
        }
      }
      RAW_BARRIER();
#pragma unroll
      for (int rt = 0; rt < 4; ++rt) {
        const int r = (rt << 4) + lr;
        bf16x4 hv;
        f32x4 cfv;
#pragma unroll
        for (int i = 0; i < 4; ++i) {
          const float cc = fsig(acc[1][rt][i]) * c0s[rt][i] +
                           fsig(acc[0][rt][i]) * ftanh(acc[2][rt][i]);
          c0s[rt][i] = cc;
          hv[i] = (__bf16)(fsig(acc[3][rt][i]) * ftanh(cc));
          cfv[i] = cc;
        }
        *reinterpret_cast<bf16x4*>(&s_h0[(r << 8) + (e0 ^ xr)]) = hv;
        if (t == 31) {
          __builtin_nontemporal_store(
              cfv, reinterpret_cast<f32x4*>(out + 69206016 + ((r0 + r) << 8) + e0));
        }
      }
      RAW_BARRIER();
    }
    {
      f32x4 acc[4][4];
#pragma unroll
      for (int q = 0; q < 4; ++q) {
        const f32x4 b = *reinterpret_cast<const f32x4*>(
            &s_b[1][(((wid << 2) + q) << 4) + (lg << 2)]);
#pragma unroll
        for (int rt = 0; rt < 4; ++rt) acc[q][rt] = b;
      }
#pragma unroll
      for (int kc8 = 0; kc8 < 16; ++kc8) {
        bf16x8 ib[4];
        const __bf16* src = (kc8 < 8) ? s_h0 : s_h1;
        const int kcl = kc8 & 7;
#pragma unroll
        for (int rt = 0; rt < 4; ++rt) {
          const int r = (rt << 4) + lr;
          ib[rt] = *reinterpret_cast<const bf16x8*>(
              &src[(r << 8) + (((kcl << 5) + (lg << 3)) ^ xr)]);
        }
#pragma unroll
        for (int q = 0; q < 4; ++q) {
          const int f = 48 + (kc8 << 2) + q;
          stage((f + 3) % 112);
          WAIT_VM3();
          __builtin_amdgcn_sched_barrier(0);
          const bf16x8 wf = ring_read(f);
#pragma unroll
          for (int rt = 0; rt < 4; ++rt) acc[q][rt] = MFMA16(wf, ib[rt], acc[q][rt]);
        }
      }
      RAW_BARRIER();
#pragma unroll
      for (int rt = 0; rt < 4; ++rt) {
        const int r = (rt << 4) + lr;
        bf16x4 hv;
        f32x4 cfv;
#pragma unroll
        for (int i = 0; i < 4; ++i) {
          const float cc = fsig(acc[1][rt][i]) * c1s[rt][i] +
                           fsig(acc[0][rt][i]) * ftanh(acc[2][rt][i]);
          c1s[rt][i] = cc;
          hv[i] = (__bf16)(fsig(acc[3][rt][i]) * ftanh(cc));
          cfv[i] = cc;
        }
        *reinterpret_cast<bf16x4*>(&s_h1[(r << 8) + (e0 ^ xr)]) = hv;
        if (t == 31) {
          __builtin_nontemporal_store(
              cfv, reinterpret_cast<f32x4*>(out + 73400320 + ((r0 + r) << 8) + e0));
        }
      }
      RAW_BARRIER();
    }
    {
#pragma unroll
      for (int j = 0; j < 4; ++j) {
        const int row = (wid << 2) + j;
        const int xw = (row & 7) << 3;
        const bf16x4 a =
            *reinterpret_cast<const bf16x4*>(&s_h1[(row << 8) + ((l << 2) ^ xw)]);
        f32x4 v;
#pragma unroll
        for (int i = 0; i < 4; ++i) v[i] = (float)a[i];
        *reinterpret_cast<f32x4*>(out + ((((r0 + row) << 5) + t) << 8) + (l << 2)) = v;
        if (t == 31) {
          *reinterpret_cast<f32x4*>(out + 71303168 + ((r0 + row) << 8) + (l << 2)) = v;
          const bf16x4 a0 = *reinterpret_cast<const bf16x4*>(
              &s_h0[(row << 8) + ((l << 2) ^ xw)]);
          f32x4 v0;
#pragma unroll
          for (int i = 0; i < 4; ++i) v0[i] = (float)a0[i];
          *reinterpret_cast<f32x4*>(out + 67108864 + ((r0 + row) << 8) + (l << 2)) = v0;
        }
      }
    }
  }
}

extern "C" void kernel_launch(void* const* d_in, const int* in_sizes, int n_in,
                              void* d_out, int out_size, void* d_ws, size_t ws_size,
                              hipStream_t stream) {
  const float* traj = (const float*)d_in[0];
  const float* Wemb = (const float*)d_in[1];
  const float* bemb = (const float*)d_in[2];
  const float* W0 = (const float*)d_in[3];
  const float* U0 = (const float*)d_in[4];
  const float* b0 = (const float*)d_in[5];
  const float* W1 = (const float*)d_in[6];
  const float* U1 = (const float*)d_in[7];
  const float* b1 = (const float*)d_in[8];
  float* out = (float*)d_out;

  __bf16* wb0 = (__bf16*)d_ws;  // 768 KB
  __bf16* wb1 = wb0 + 393216;   // 1 MB
  const size_t slab_off = 1835008;
  const size_t slab_bytes = (size_t)8192 * 32 * 256 * 2;  // 134217728

  hipLaunchKernelGGL(prep_w0, dim3(1536), dim3(256), 0, stream, W0, U0, wb0);
  hipLaunchKernelGGL(prep_w1, dim3(2048), dim3(256), 0, stream, W1, U1, wb1);

  if (ws_size >= slab_off + slab_bytes) {
    __bf16* slab = (__bf16*)((char*)d_ws + slab_off);
    hipLaunchKernelGGL(lstm_l0, dim3(256), dim3(1024), 0, stream,
                       traj, Wemb, bemb, b0, wb0, out, slab);
    hipLaunchKernelGGL(lstm_l1, dim3(256), dim3(1024), 0, stream,
                       b1, wb1, slab, out);
  } else {
    hipLaunchKernelGGL(lstm_fused, dim3(128), dim3(1024), 0, stream,
                       traj, Wemb, bemb, b0, b1, wb0, wb1, out);
  }
}